// Round 2
// baseline (604.288 us; speedup 1.0000x reference)
//
#include <hip/hip_runtime.h>
#include <hip/hip_bf16.h>

#define DOUT 128
#define DIN  256
#define BROWS 64            // rows per bucket
#define MAXNB 1024          // bucket-scan width cap (nb = ceil(N/64) = 782)
#define BIN_CHUNK 4096      // edges per bin_edges block
#define SCHUNK 9216         // edges per spmm LDS chunk (mean 8184 + 11 sigma)

static __device__ __forceinline__ float bf16lo_to_f(unsigned u) {
    return __uint_as_float(u << 16);
}
static __device__ __forceinline__ float bf16hi_to_f(unsigned u) {
    return __uint_as_float(u & 0xffff0000u);
}
static __device__ __forceinline__ unsigned f_to_bf16_bits(float f) {
    unsigned u = __float_as_uint(f);               // RNE round to bf16
    return (u + 0x7fffu + ((u >> 16) & 1u)) >> 16;
}

// ======================= hV = h @ V, bf16 output (validated r5/r6) =========
__global__ __launch_bounds__(256) void hv_gemm(const float* __restrict__ h,
                                               const float* __restrict__ V,
                                               unsigned short* __restrict__ hV,
                                               int N) {
    __shared__ __align__(16) float hsT[DOUT][36];
    int r0 = blockIdx.x * 32;
    int t = threadIdx.x, col = t & 127, g = t >> 7;
    {
        int row = t >> 3, kb = t & 7;
        int sr = min(r0 + row, N - 1);
        const float4* hr = (const float4*)(h + (size_t)sr * DOUT);
        for (int i = 0; i < 4; ++i) {
            int k4 = kb + 8 * i; float4 v4 = hr[k4]; int k = 4 * k4;
            hsT[k][row] = v4.x; hsT[k+1][row] = v4.y;
            hsT[k+2][row] = v4.z; hsT[k+3][row] = v4.w;
        }
    }
    __syncthreads();
    float acc[16];
#pragma unroll
    for (int j = 0; j < 16; ++j) acc[j] = 0.f;
    int rb = g * 16;
#pragma unroll 2
    for (int k = 0; k < DOUT; ++k) {
        float v = V[k * DOUT + col];
        const float4* hp = (const float4*)&hsT[k][rb];
        float4 a0 = hp[0], a1 = hp[1], a2 = hp[2], a3 = hp[3];
        acc[0] += v*a0.x; acc[1] += v*a0.y; acc[2] += v*a0.z; acc[3] += v*a0.w;
        acc[4] += v*a1.x; acc[5] += v*a1.y; acc[6] += v*a1.z; acc[7] += v*a1.w;
        acc[8] += v*a2.x; acc[9] += v*a2.y; acc[10]+= v*a2.z; acc[11]+= v*a2.w;
        acc[12]+= v*a3.x; acc[13]+= v*a3.y; acc[14]+= v*a3.z; acc[15]+= v*a3.w;
    }
#pragma unroll
    for (int j = 0; j < 16; ++j) {
        int r = r0 + rb + j;
        if (r < N) hV[(size_t)r * DOUT + col] = (unsigned short)f_to_bf16_bits(acc[j]);
    }
}

// ======================= bucket histogram (validated r5) ===================
__global__ void bucket_hist(const int* __restrict__ rows, int* __restrict__ gcnt,
                            int nE, int nb) {
    __shared__ int hc[MAXNB];
    for (int i = threadIdx.x; i < nb; i += blockDim.x) hc[i] = 0;
    __syncthreads();
    for (int i = blockIdx.x * blockDim.x + threadIdx.x; i < nE;
         i += gridDim.x * blockDim.x)
        atomicAdd(&hc[rows[i] / BROWS], 1);
    __syncthreads();
    for (int i = threadIdx.x; i < nb; i += blockDim.x)
        if (hc[i]) atomicAdd(&gcnt[i], hc[i]);
}

// ============ exclusive scan of bucket counts (validated r5) ===============
__global__ __launch_bounds__(1024) void scan_buckets(const int* __restrict__ gcnt,
                                                     int* __restrict__ bptr,
                                                     int* __restrict__ gcur, int nb) {
    __shared__ int sbuf[MAXNB];
    int t = threadIdx.x;
    int c = (t < nb) ? gcnt[t] : 0;
    sbuf[t] = c;
    __syncthreads();
    for (int off = 1; off < 1024; off <<= 1) {
        int v = (t >= off) ? sbuf[t - off] : 0;
        __syncthreads();
        sbuf[t] += v;
        __syncthreads();
    }
    if (t == 0) bptr[0] = 0;
    if (t < nb) { bptr[t + 1] = sbuf[t]; gcur[t] = sbuf[t] - c; }
}

// ===== bin edges into bucket-major order, LDS counting sort ================
// NEW: emits pre-converted 4B record ecv4 = (col<<16)|bf16(val) plus a 1B
// local-row array erow (row & 63). bf16 conversion now happens exactly once
// here (same value as before -> bit-identical results), and spmm's sort
// phases read 6B/edge instead of 16B/edge.
__global__ __launch_bounds__(1024) void bin_edges(const int* __restrict__ rows,
                                                  const int* __restrict__ cols,
                                                  const float* __restrict__ vals,
                                                  int* __restrict__ gcur,
                                                  unsigned* __restrict__ ecv4,
                                                  unsigned char* __restrict__ erow,
                                                  int nE, int nb) {
    __shared__ unsigned secv[BIN_CHUNK];                   // 16 KB
    __shared__ unsigned short srow16[BIN_CHUNK];           // 8 KB
    __shared__ int hcnt[MAXNB], sbuf[MAXNB], loff[MAXNB], lcur[MAXNB], gbase[MAXNB];
    int t = threadIdx.x;
    int base = blockIdx.x * BIN_CHUNK;
    int nvalid = min(BIN_CHUNK, nE - base);
    hcnt[t] = 0;
    __syncthreads();
    for (int j = t; j < nvalid; j += 1024)            // A: local hist
        atomicAdd(&hcnt[rows[base + j] / BROWS], 1);
    __syncthreads();
    int myc = hcnt[t];                                 // B: scan
    sbuf[t] = myc;
    __syncthreads();
    for (int off = 1; off < 1024; off <<= 1) {
        int v = (t >= off) ? sbuf[t - off] : 0;
        __syncthreads();
        sbuf[t] += v;
        __syncthreads();
    }
    int excl = sbuf[t] - myc;
    loff[t] = excl;
    lcur[t] = excl;
    if (t < nb && myc > 0) gbase[t] = atomicAdd(&gcur[t], myc);  // C: reserve
    __syncthreads();
    for (int j = t; j < nvalid; j += 1024) {          // D: place into LDS
        int i = base + j;
        unsigned r = (unsigned)rows[i];
        int bk = (int)r / BROWS;
        int slot = atomicAdd(&lcur[bk], 1);
        secv[slot] = ((unsigned)cols[i] << 16) | f_to_bf16_bits(vals[i]);
        srow16[slot] = (unsigned short)r;
    }
    __syncthreads();
    for (int j = t; j < nvalid; j += 1024) {          // E: coalesced write-out
        unsigned r = srow16[j];
        int bk = (int)r / BROWS;
        int dst = gbase[bk] + (j - loff[bk]);
        ecv4[dst] = secv[j];
        erow[dst] = (unsigned char)(r & (BROWS - 1));
    }
}

// ============== SPMM on buckets: row-sort chunk in LDS, reg accumulate =====
// One block (512 thr, 8 waves) per bucket of 64 rows. Wave w owns rows
// w*8..w*8+7. NEW half-wave edge split: lanes 0-31 process edges 4g..4g+3
// of each 8-group, lanes 32-63 process edges 4g+4..4g+7; each lane covers
// 4 output cols (4*cl..4*cl+3) via one dwordx2 gather per edge -> 2 edges
// per VMEM instruction, half the address math. Cross-half combine is one
// __shfl_xor(32) per row at writeback. Segments padded to multiples of 8
// (pad record = 0 -> col 0, val +0.0 -> no contribution).
__global__ __launch_bounds__(512) void spmm_sorted(const int* __restrict__ bptr,
                                                   const unsigned* __restrict__ ecv4,
                                                   const unsigned char* __restrict__ erow,
                                                   const unsigned* __restrict__ hV,
                                                   float* __restrict__ out, int N) {
    __shared__ __align__(16) unsigned srec[SCHUNK + BROWS * 8];  // ~38 KB
    __shared__ int rcnt[BROWS], sbuf[BROWS], rptr[BROWS + 1], rcur[BROWS];
    int t = threadIdx.x;
    int b = blockIdx.x;
    int wave = t >> 6, lane = t & 63;
    int hf = lane >> 5;                                // half index 0/1
    int cl = lane & 31;                                // col block: 4*cl..4*cl+3
    int beg = bptr[b], end = bptr[b + 1];
    const uint2* hv2 = (const uint2*)hV;               // row stride = 32 uint2

    float4 acc[8];
#pragma unroll
    for (int j = 0; j < 8; ++j) acc[j] = make_float4(0.f, 0.f, 0.f, 0.f);

    for (int cb = beg; cb < end; cb += SCHUNK) {
        int nval = min(SCHUNK, end - cb);
        if (t < BROWS) rcnt[t] = 0;
        __syncthreads();
        for (int j = t; j < nval; j += 512)            // hist by local row (1B read)
            atomicAdd(&rcnt[erow[cb + j]], 1);
        __syncthreads();
        int c = (t < BROWS) ? rcnt[t] : 0;             // scan PADDED counts
        int cp = (c + 7) & ~7;
        if (t < BROWS) sbuf[t] = cp;
        __syncthreads();
        for (int off = 1; off < BROWS; off <<= 1) {
            int add = (t < BROWS && t >= off) ? sbuf[t - off] : 0;
            __syncthreads();
            if (t < BROWS) sbuf[t] += add;
            __syncthreads();
        }
        if (t == 0) rptr[0] = 0;
        if (t < BROWS) { rptr[t + 1] = sbuf[t]; rcur[t] = sbuf[t] - cp; }
        __syncthreads();
        for (int j = t; j < nval; j += 512) {          // place sorted-by-row (5B read)
            int rloc = erow[cb + j];
            int slot = atomicAdd(&rcur[rloc], 1);
            srec[slot] = ecv4[cb + j];
        }
        __syncthreads();
        if (t < BROWS) {                               // zero-fill pad slots
            int e0 = rcur[t];
            int e1 = rptr[t + 1];
            for (int k = e0; k < e1; ++k) srec[k] = 0u;
        }
        __syncthreads();
        // compute: wave-uniform segment bounds; per 8-edge group each half
        // issues 4 dwordx2 gathers (2 edges per wave VMEM instruction)
#pragma unroll
        for (int rr = 0; rr < 8; ++rr) {
            int rloc = wave * 8 + rr;
            int s = rptr[rloc];
            int ng = (rptr[rloc + 1] - s) >> 3;        // groups of 8 edges
            const uint4* sp = (const uint4*)&srec[s + 4 * hf];  // 16B-aligned
            float4 a = acc[rr];
            for (int g = 0; g < ng; ++g) {
                uint4 q = sp[2 * g];                   // this half's 4 records
                uint2 u0 = hv2[((q.x >> 16) << 5) | cl];
                uint2 u1 = hv2[((q.y >> 16) << 5) | cl];
                uint2 u2 = hv2[((q.z >> 16) << 5) | cl];
                uint2 u3 = hv2[((q.w >> 16) << 5) | cl];
                float v0 = bf16lo_to_f(q.x);
                float v1 = bf16lo_to_f(q.y);
                float v2 = bf16lo_to_f(q.z);
                float v3 = bf16lo_to_f(q.w);
                a.x += v0 * bf16lo_to_f(u0.x); a.y += v0 * bf16hi_to_f(u0.x);
                a.z += v0 * bf16lo_to_f(u0.y); a.w += v0 * bf16hi_to_f(u0.y);
                a.x += v1 * bf16lo_to_f(u1.x); a.y += v1 * bf16hi_to_f(u1.x);
                a.z += v1 * bf16lo_to_f(u1.y); a.w += v1 * bf16hi_to_f(u1.y);
                a.x += v2 * bf16lo_to_f(u2.x); a.y += v2 * bf16hi_to_f(u2.x);
                a.z += v2 * bf16lo_to_f(u2.y); a.w += v2 * bf16hi_to_f(u2.y);
                a.x += v3 * bf16lo_to_f(u3.x); a.y += v3 * bf16hi_to_f(u3.x);
                a.z += v3 * bf16lo_to_f(u3.y); a.w += v3 * bf16hi_to_f(u3.y);
            }
            acc[rr] = a;
        }
        __syncthreads();
    }
#pragma unroll
    for (int rr = 0; rr < 8; ++rr) {                   // combine halves + store
        float4 a = acc[rr];
        a.x += __shfl_xor(a.x, 32);
        a.y += __shfl_xor(a.y, 32);
        a.z += __shfl_xor(a.z, 32);
        a.w += __shfl_xor(a.w, 32);
        int gr = b * BROWS + wave * 8 + rr;
        if (hf == 0 && gr < N)
            ((float4*)(out + (size_t)gr * DOUT))[cl] = a;
    }
}

// =============== epilogue: out = relu(x@W + out) in place (valid. r5/r6) ===
__global__ __launch_bounds__(256) void epi_xw(const float* __restrict__ x,
                                              const float* __restrict__ W,
                                              float* __restrict__ out, int N) {
    __shared__ __align__(16) float xsT[DIN][36];
    int r0 = blockIdx.x * 32;
    int t = threadIdx.x, col = t & 127, g = t >> 7;
    {
        int row = t >> 3, kb = t & 7;
        int sr = min(r0 + row, N - 1);
        const float4* xr = (const float4*)(x + (size_t)sr * DIN);
        for (int i = 0; i < 8; ++i) {
            int k4 = kb + 8 * i; float4 v4 = xr[k4]; int k = 4 * k4;
            xsT[k][row] = v4.x; xsT[k+1][row] = v4.y;
            xsT[k+2][row] = v4.z; xsT[k+3][row] = v4.w;
        }
    }
    __syncthreads();
    float acc[16];
#pragma unroll
    for (int j = 0; j < 16; ++j) acc[j] = 0.f;
    int rb = g * 16;
#pragma unroll 2
    for (int k = 0; k < DIN; ++k) {
        float w = W[k * DOUT + col];
        const float4* xp = (const float4*)&xsT[k][rb];
        float4 a0 = xp[0], a1 = xp[1], a2 = xp[2], a3 = xp[3];
        acc[0] += w*a0.x; acc[1] += w*a0.y; acc[2] += w*a0.z; acc[3] += w*a0.w;
        acc[4] += w*a1.x; acc[5] += w*a1.y; acc[6] += w*a1.z; acc[7] += w*a1.w;
        acc[8] += w*a2.x; acc[9] += w*a2.y; acc[10]+= w*a2.z; acc[11]+= w*a2.w;
        acc[12]+= w*a3.x; acc[13]+= w*a3.y; acc[14]+= w*a3.z; acc[15]+= w*a3.w;
    }
#pragma unroll
    for (int j = 0; j < 16; ++j) {
        int r = r0 + rb + j;
        if (r < N) {
            size_t o = (size_t)r * DOUT + col;
            out[o] = fmaxf(acc[j] + out[o], 0.f);
        }
    }
}

// ==================== fallback path (ws too small / N too big) =============
__global__ void spmm_atomic(const int* __restrict__ rows,
                            const int* __restrict__ cols,
                            const float* __restrict__ vals,
                            const float* __restrict__ h,
                            float* __restrict__ S, int nEdges) {
    int wave = (int)((blockIdx.x * blockDim.x + threadIdx.x) >> 6);
    int lane = threadIdx.x & 63;
    if (wave >= nEdges) return;
    int r = rows[wave], c = cols[wave];
    float v = vals[wave];
    float2 hv = ((const float2*)(h + (size_t)c * DOUT))[lane];
    float* srow = S + (size_t)r * DOUT;
    atomicAdd(srow + 2 * lane,     v * hv.x);
    atomicAdd(srow + 2 * lane + 1, v * hv.y);
}

__global__ __launch_bounds__(256) void fused_out_full(const float* __restrict__ x,
                                                      const float* __restrict__ W,
                                                      const float* __restrict__ V,
                                                      float* __restrict__ out, int N) {
    __shared__ float xs[DIN];
    __shared__ float ss[DOUT];
    int r = blockIdx.x;
    int col = threadIdx.x & 127;
    if (threadIdx.x < 128) {
        float2 xv = ((const float2*)(x + (size_t)r * DIN))[col];
        xs[2 * col] = xv.x; xs[2 * col + 1] = xv.y;
        ss[col] = out[(size_t)r * DOUT + col];
    }
    __syncthreads();
    if (threadIdx.x >= 128) return;
    float acc = 0.f;
    for (int k = 0; k < DIN; ++k) acc += xs[k] * W[k * DOUT + col];
    for (int k = 0; k < DOUT; ++k) acc += ss[k] * V[k * DOUT + col];
    out[(size_t)r * DOUT + col] = fmaxf(acc, 0.f);
}

static inline size_t align256(size_t v) { return (v + 255) & ~(size_t)255; }

extern "C" void kernel_launch(void* const* d_in, const int* in_sizes, int n_in,
                              void* d_out, int out_size, void* d_ws, size_t ws_size,
                              hipStream_t stream) {
    const float* x    = (const float*)d_in[0];
    const float* h    = (const float*)d_in[1];
    const int*   rows = (const int*)d_in[2];
    const int*   cols = (const int*)d_in[3];
    const float* vals = (const float*)d_in[4];
    const float* W    = (const float*)d_in[5];
    const float* V    = (const float*)d_in[6];
    // d_in[7] (alpha): softmax over a size-1 axis == 1 -> dead.

    int nE = in_sizes[2];              // D*E = 6.4M
    int N  = in_sizes[1] / DOUT;       // 50000
    int nb = (N + BROWS - 1) / BROWS;  // 782 buckets
    float* out = (float*)d_out;

    // ws: hV[N*128 bf16] | gcnt | bptr | gcur | ecv4[nE u32] | erow[nE u8]
    size_t o_hV   = 0;
    size_t o_gcnt = o_hV   + align256((size_t)N * DOUT * 2);
    size_t o_bptr = o_gcnt + align256((size_t)nb * 4);
    size_t o_gcur = o_bptr + align256((size_t)(nb + 1) * 4);
    size_t o_ecv4 = o_gcur + align256((size_t)nb * 4);
    size_t o_erow = o_ecv4 + align256((size_t)nE * 4);
    size_t need   = o_erow + (size_t)nE;

    if (ws_size >= need && N < 65536 && nb <= MAXNB) {
        char* p = (char*)d_ws;
        unsigned short* hV = (unsigned short*)(p + o_hV);
        int*      gcnt = (int*)(p + o_gcnt);
        int*      bptr = (int*)(p + o_bptr);
        int*      gcur = (int*)(p + o_gcur);
        unsigned* ecv4 = (unsigned*)(p + o_ecv4);
        unsigned char* erow = (unsigned char*)(p + o_erow);

        hv_gemm<<<(N + 31) / 32, 256, 0, stream>>>(h, V, hV, N);
        hipMemsetAsync(gcnt, 0, (size_t)nb * 4, stream);
        bucket_hist<<<1024, 256, 0, stream>>>(rows, gcnt, nE, nb);
        scan_buckets<<<1, 1024, 0, stream>>>(gcnt, bptr, gcur, nb);
        bin_edges<<<(nE + BIN_CHUNK - 1) / BIN_CHUNK, 1024, 0, stream>>>(
            rows, cols, vals, gcur, ecv4, erow, nE, nb);
        spmm_sorted<<<nb, 512, 0, stream>>>(bptr, ecv4, erow, (const unsigned*)hV,
                                            out, N);
        epi_xw<<<(N + 31) / 32, 256, 0, stream>>>(x, W, out, N);
    } else {
        hipMemsetAsync(out, 0, (size_t)N * DOUT * 4, stream);
        spmm_atomic<<<(nE + 3) / 4, 256, 0, stream>>>(rows, cols, vals, h, out, nE);
        fused_out_full<<<N, 128, 0, stream>>>(x, W, V, out, N);
    }
}